// Round 14
// baseline (32.923 us; speedup 1.0000x reference)
//
#include <hip/hip_runtime.h>

#define NCLS 24
#define NB 8
#define NCH 128
#define WLO 128
#define WHI 512
#define CELLS (128*128)
#define SUBT 256                    // subtiles (blocks) per batch
#define NBLK (NB * SUBT)            // 2048
#define KCH (NCLS * NCH)            // 3072
#define NF (NB * KCH)               // 24576

typedef _Float16 f16x8 __attribute__((ext_vector_type(8)));
typedef float    f32x4 __attribute__((ext_vector_type(4)));

// hist swizzle (f32 elem within 64-cell row): e ^ ((cls&7)<<2).
// A-frag b128 reads land 8-uniform on bank-quads (optimal); bijective per row.
#define HSWZ(c_, e_) ((e_) ^ (((c_) & 7) << 2))

// LDS-visibility barrier WITHOUT vmcnt drain (DMAs ride through).
__device__ __forceinline__ void barrier_nodrain() {
    asm volatile("s_waitcnt lgkmcnt(0)" ::: "memory");
    __builtin_amdgcn_s_barrier();
}

// Direct global->LDS DMA, 16 B/lane, zero VGPR staging (compiler can't sink it).
__device__ __forceinline__ void load_lds16(const float* g, float* l) {
    __builtin_amdgcn_global_load_lds(
        (const __attribute__((address_space(1))) void*)g,
        (__attribute__((address_space(3))) void*)l, 16, 0, 0);
}

// One block = one 64-cell subtile. Tile staged f32 via DMA with PRE-SWIZZLED
// per-lane source (oct ^= ch&7) so swizzled ds_read_b128 is conflict-optimal.
// Tile rows are wave-private (stage & consume same 32 channels) -> no barrier,
// only a wave-local vmcnt(0). Hist: 2 lgkm-only barriers.
__global__ __launch_bounds__(256, 4)
void fm_main(const float* __restrict__ data, const int* __restrict__ label,
             _Float16* __restrict__ part, float* __restrict__ cpart)
{
    __shared__ float tile[NCH * 64];          // 32 KB, [ch][oct^(ch&7) cells] f32
    __shared__ float histf[32 * 64];          // 8 KB, rows 24-31 stay zero (A-pad)

    const int bid  = blockIdx.x;
    const int b    = bid >> 8;
    const int grp  = bid & 255;               // subtile index
    const int tid  = threadIdx.x;

    const int w    = tid >> 6;        // wave id (= label hi-res row 0..3)
    const int lane = tid & 63;
    const int l15  = lane & 15, lg = lane >> 4;
    const int cl   = lane;            // label cell / histogram cell
    const int wb   = w * 32;          // this wave's channel base

    const int y  = grp >> 1;
    const int x0 = (grp & 1) << 6;
    const int cb = y * WLO + x0;

    const float* dbase = data  + (size_t)b * NCH * CELLS + cb;
    const int*   lbase = label + (size_t)b * (WHI * WHI) + (size_t)(4 * y + w) * WHI + x0 * 4;

    // ---- label load FIRST (oldest in vmcnt -> atomics start while DMAs fly) ----
    const int4 lv = *reinterpret_cast<const int4*>(lbase + cl * 4);
    __builtin_amdgcn_sched_barrier(0);

    // ---- bulk-issue 8 DMAs: DMA k stages channels wb+4k..+3, 64 cells each.
    //      dest octet (ch, o') gets source cells octet o = o' ^ (ch&7):
    //      lane l -> ch = base + (l>>4), o' = l&15, src oct = (l&15)^(ch&7).
#pragma unroll
    for (int k = 0; k < 8; ++k) {
        const int ch = wb + k * 4 + lg;
        load_lds16(dbase + (size_t)ch * CELLS + ((l15 ^ (ch & 7)) << 2),
                   &tile[(wb + k * 4) * 64]);
    }
    __builtin_amdgcn_sched_barrier(0);

    // ---- zero histogram (2048 f32 = 2 f32x4/thread, 8-uniform quads) ----
    reinterpret_cast<f32x4*>(histf)[tid]       = (f32x4){0.f, 0.f, 0.f, 0.f};
    reinterpret_cast<f32x4*>(histf)[tid + 256] = (f32x4){0.f, 0.f, 0.f, 0.f};
    barrier_nodrain();                         // B1: zeros visible; DMAs in flight

    // ---- histogram atomics (lane-distinct cells; waits vmcnt(8) for lv only) ----
    if ((unsigned)lv.x < 24u) atomicAdd(&histf[lv.x * 64 + HSWZ(lv.x, cl)], 1.f);
    if ((unsigned)lv.y < 24u) atomicAdd(&histf[lv.y * 64 + HSWZ(lv.y, cl)], 1.f);
    if ((unsigned)lv.z < 24u) atomicAdd(&histf[lv.z * 64 + HSWZ(lv.z, cl)], 1.f);
    if ((unsigned)lv.w < 24u) atomicAdd(&histf[lv.w * 64 + HSWZ(lv.w, cl)], 1.f);
    barrier_nodrain();                         // B2: all atomics retired

    // ---- A fragments from swizzled hist; count partials from same reads ----
    f16x8 af[2][2];
    float cs0 = 0.f, cs1 = 0.f;
#pragma unroll
    for (int mt = 0; mt < 2; ++mt)
#pragma unroll
        for (int kt = 0; kt < 2; ++kt) {
            const int cls = mt * 16 + l15;
            const int e0  = kt * 32 + lg * 8;
            const f32x4 h0 = *(const f32x4*)&histf[cls * 64 + HSWZ(cls, e0)];
            const f32x4 h1 = *(const f32x4*)&histf[cls * 64 + HSWZ(cls, e0 + 4)];
            f16x8 a;
            a[0] = (_Float16)h0.x; a[1] = (_Float16)h0.y; a[2] = (_Float16)h0.z; a[3] = (_Float16)h0.w;
            a[4] = (_Float16)h1.x; a[5] = (_Float16)h1.y; a[6] = (_Float16)h1.z; a[7] = (_Float16)h1.w;
            af[mt][kt] = a;
            const float p = (h0.x + h0.y) + (h0.z + h0.w) + (h1.x + h1.y) + (h1.z + h1.w);
            if (mt == 0) cs0 += p; else cs1 += p;
        }

    // ---- wave-local wait for OWN tile DMAs; fence ds_reads below it ----
    asm volatile("s_waitcnt vmcnt(0)" ::: "memory");
    __builtin_amdgcn_sched_barrier(0);

    // ---- B fragments: swizzled reads (8-uniform quads), cvt f32->f16 ----
    f16x8 bf[2][2];
#pragma unroll
    for (int nt = 0; nt < 2; ++nt)
#pragma unroll
        for (int kt = 0; kt < 2; ++kt) {
            const int row = wb + nt * 16 + l15;
            const int m0  = kt * 8 + lg * 2;           // source cell octets m0, m0+1
            const f32x4 b0 = *(const f32x4*)&tile[row * 64 + (( m0      ^ (row & 7)) << 2)];
            const f32x4 b1 = *(const f32x4*)&tile[row * 64 + (((m0 + 1) ^ (row & 7)) << 2)];
            f16x8 v;
            v[0] = (_Float16)b0.x; v[1] = (_Float16)b0.y; v[2] = (_Float16)b0.z; v[3] = (_Float16)b0.w;
            v[4] = (_Float16)b1.x; v[5] = (_Float16)b1.y; v[6] = (_Float16)b1.z; v[7] = (_Float16)b1.w;
            bf[nt][kt] = v;
        }

    // ---- 8 MFMAs ----
    f32x4 acc[2][2];
#pragma unroll
    for (int mt = 0; mt < 2; ++mt)
#pragma unroll
        for (int nt = 0; nt < 2; ++nt) {
            acc[mt][nt] = (f32x4){0.f, 0.f, 0.f, 0.f};
#pragma unroll
            for (int kt = 0; kt < 2; ++kt)
                acc[mt][nt] = __builtin_amdgcn_mfma_f32_16x16x32_f16(
                    af[mt][kt], bf[nt][kt], acc[mt][nt], 0, 0, 0);
        }

    // ---- counts: butterfly over 4 k-groups; wave 0 lanes write ----
    cs0 += __shfl_xor(cs0, 16, 64); cs0 += __shfl_xor(cs0, 32, 64);
    cs1 += __shfl_xor(cs1, 16, 64); cs1 += __shfl_xor(cs1, 32, 64);
    if (w == 0 && lane < 16) {
        cpart[(size_t)bid * NCLS + lane] = cs0;
        if (lane < 8) cpart[(size_t)bid * NCLS + 16 + lane] = cs1;
    }

    // ---- flush f16 per-block partials (non-atomic) ----
    _Float16* pblk = part + (size_t)bid * KCH;
#pragma unroll
    for (int mt = 0; mt < 2; ++mt)
#pragma unroll
        for (int nt = 0; nt < 2; ++nt)
#pragma unroll
            for (int rg = 0; rg < 4; ++rg) {
                const int cls = mt * 16 + lg * 4 + rg;    // C/D: row=(lane>>4)*4+reg
                const int ch  = wb + nt * 16 + l15;       //      col=lane&15
                if (cls < NCLS) pblk[cls * NCH + ch] = (_Float16)acc[mt][nt][rg];
            }
}

// Grid 384 = (b, cls, ch-half). 4 waves reduce 64 g's each -> LDS -> wave-0 finish.
__global__ __launch_bounds__(256)
void fm_final(const _Float16* __restrict__ part, const float* __restrict__ cpart,
              float* __restrict__ out)
{
    __shared__ float red[256];
    __shared__ float credv[256];
    const int bid  = blockIdx.x;
    const int b    = bid / (NCLS * 2);
    const int rem  = bid % (NCLS * 2);
    const int cls  = rem >> 1;
    const int half = rem & 1;
    const int t    = threadIdx.x;
    const int c    = t & 63;           // channel within half
    const int gq   = t >> 6;           // g-quarter 0..3

    credv[t] = cpart[(size_t)(b * SUBT + t) * NCLS + cls];

    const _Float16* pb = part + (size_t)(b * SUBT + gq * 64) * KCH + cls * NCH + half * 64 + c;
    float s = 0.f;
#pragma unroll 8
    for (int g = 0; g < 64; ++g) s += (float)pb[(size_t)g * KCH];
    red[t] = s;
    __syncthreads();

    if (t < 64) {
        float cnt = credv[t] + credv[t + 64] + credv[t + 128] + credv[t + 192];
#pragma unroll
        for (int o = 32; o >= 1; o >>= 1) cnt += __shfl_xor(cnt, o, 64);
        const float sf = red[t] + red[t + 64] + red[t + 128] + red[t + 192];
        out[(size_t)b * KCH + (half * 64 + t) * NCLS + cls] = sf / (cnt + 1e-8f);  // (B,C,NCLS)
        if (t == 0 && half == 0) out[NF + b * NCLS + cls] = (cnt > 0.f) ? 1.f : 0.f;
    }
}

extern "C" void kernel_launch(void* const* d_in, const int* in_sizes, int n_in,
                              void* d_out, int out_size, void* d_ws, size_t ws_size,
                              hipStream_t stream) {
    const float* data  = (const float*)d_in[0];
    const int*   label = (const int*)d_in[1];
    float*     out   = (float*)d_out;
    _Float16*  part  = (_Float16*)d_ws;                          // NBLK*3072 f16 (12.6 MB)
    float*     cpart = (float*)(part + (size_t)NBLK * KCH);      // NBLK*24 f32

    fm_main<<<dim3(NBLK), dim3(256), 0, stream>>>(data, label, part, cpart);
    fm_final<<<dim3(NB * NCLS * 2), dim3(256), 0, stream>>>(part, cpart, out);
}

// Round 15
// 26.031 us; speedup vs baseline: 1.2648x; 1.2648x over previous
//
#include <hip/hip_runtime.h>

#define NCLS 24
#define NB 8
#define NCH 128
#define WLO 128
#define WHI 512
#define CELLS (128*128)
#define BPB 128                     // blocks per batch (2 subtiles each)
#define NBLK (NB * BPB)             // 1024
#define KCH (NCLS * NCH)            // 3072
#define NF (NB * KCH)               // 24576

typedef _Float16 f16x4 __attribute__((ext_vector_type(4)));
typedef _Float16 f16x8 __attribute__((ext_vector_type(8)));
typedef float    f32x4 __attribute__((ext_vector_type(4)));
typedef int      i32x4 __attribute__((ext_vector_type(4)));

#define HSWZ(c_, e_) ((e_) ^ (((c_) & 7) << 3))

__device__ __forceinline__ void barrier_nodrain() {
    asm volatile("s_waitcnt lgkmcnt(0)" ::: "memory");
    __builtin_amdgcn_s_barrier();
}
// Counted VMEM wait + hard schedule fence (rule 18: fence AFTER the wait).
#define VMWAIT(N) do { asm volatile("s_waitcnt vmcnt(" #N ")" ::: "memory"); \
                       __builtin_amdgcn_sched_barrier(0); } while (0)

// Compiler-opaque loads: cannot be sunk/serialized; WE manage vmcnt.
__device__ __forceinline__ f32x4 gload_f4(const float* p) {
    f32x4 r;
    asm volatile("global_load_dwordx4 %0, %1, off" : "=v"(r) : "v"(p));
    return r;
}
__device__ __forceinline__ i32x4 gload_i4(const int* p) {
    i32x4 r;
    asm volatile("global_load_dwordx4 %0, %1, off" : "=v"(r) : "v"(p));
    return r;
}

// One block = one 128-cell row = 2 subtiles; acc carried in regs; hand-scheduled
// loads: 10 in flight at launch, 8 across the subtile-0 compute phase.
__global__ __launch_bounds__(256, 4)
void fm_main(const float* __restrict__ data, const int* __restrict__ label,
             _Float16* __restrict__ part, float* __restrict__ cpart)
{
    __shared__ float    histf[32 * 64];       // 8 KB, rows 24-31 stay zero
    __shared__ _Float16 tile[NCH * 64];       // 16 KB, [ch][cell swz]

    const int bid  = blockIdx.x;
    const int b    = bid >> 7;
    const int grp  = bid & 127;               // cell row
    const int tid  = threadIdx.x;

    const int q    = tid & 15;        // float4 slot (4 cells)
    const int chb  = tid >> 4;        // channel base 0..15
    const int cl   = tid & 63;        // label/hist cell
    const int w    = tid >> 6;        // wave id (= label hi-res row)
    const int lane = tid & 63;

    const float* dbase = data  + (size_t)b * NCH * CELLS + grp * WLO;
    const int*   lbase = label + (size_t)b * (WHI * WHI) + (size_t)(4 * grp + w) * WHI;

    // ---- issue: labels first (oldest), then subtile-0 data. 10 in flight. ----
    const i32x4 lv0 = gload_i4(lbase + cl * 4);
    const i32x4 lv1 = gload_i4(lbase + 256 + cl * 4);
    f32x4 v[8];
#pragma unroll
    for (int k = 0; k < 8; ++k)
        v[k] = gload_f4(dbase + (size_t)(chb + k * 16) * CELLS + q * 4);
    __builtin_amdgcn_sched_barrier(0);

    f32x4 acc[2][2];
#pragma unroll
    for (int mt = 0; mt < 2; ++mt)
#pragma unroll
        for (int nt = 0; nt < 2; ++nt) acc[mt][nt] = (f32x4){0.f, 0.f, 0.f, 0.f};
    float cs0 = 0.f, cs1 = 0.f;

    // ================= subtile 0 =================
#pragma unroll
    for (int k = 0; k < 8; ++k) histf[tid + k * 256] = 0.f;
    barrier_nodrain();

    VMWAIT(8);                                // lv0,lv1 landed; data still flying
    if ((unsigned)lv0[0] < 24u) atomicAdd(&histf[lv0[0] * 64 + HSWZ(lv0[0], cl)], 1.f);
    if ((unsigned)lv0[1] < 24u) atomicAdd(&histf[lv0[1] * 64 + HSWZ(lv0[1], cl)], 1.f);
    if ((unsigned)lv0[2] < 24u) atomicAdd(&histf[lv0[2] * 64 + HSWZ(lv0[2], cl)], 1.f);
    if ((unsigned)lv0[3] < 24u) atomicAdd(&histf[lv0[3] * 64 + HSWZ(lv0[3], cl)], 1.f);

    VMWAIT(0);                                // subtile-0 data landed
#pragma unroll
    for (int k = 0; k < 8; ++k) {
        const int ch = chb + k * 16;
        f16x4 hv;
        hv[0] = (_Float16)v[k][0]; hv[1] = (_Float16)v[k][1];
        hv[2] = (_Float16)v[k][2]; hv[3] = (_Float16)v[k][3];
        const int idx = ch * 64 + ((((q >> 1) ^ (ch & 7)) << 3) | ((q & 1) << 2));
        *reinterpret_cast<f16x4*>(&tile[idx]) = hv;
    }
    // ---- issue subtile-1 data NOW; drains only after MFMA-0 ----
#pragma unroll
    for (int k = 0; k < 8; ++k)
        v[k] = gload_f4(dbase + 64 + (size_t)(chb + k * 16) * CELLS + q * 4);
    __builtin_amdgcn_sched_barrier(0);
    barrier_nodrain();

#pragma unroll
    for (int s = 0; s < 2; ++s) {
        // ---- A fragments + count partials ----
        f16x8 af[2][2];
#pragma unroll
        for (int mt = 0; mt < 2; ++mt)
#pragma unroll
            for (int kt = 0; kt < 2; ++kt) {
                const int cls = mt * 16 + (lane & 15);
                const int e0  = kt * 32 + (lane >> 4) * 8;
                const float* hp = &histf[cls * 64 + HSWZ(cls, e0)];
                const f32x4 h0 = *reinterpret_cast<const f32x4*>(hp);
                const f32x4 h1 = *reinterpret_cast<const f32x4*>(hp + 4);
                f16x8 a;
                a[0] = (_Float16)h0[0]; a[1] = (_Float16)h0[1]; a[2] = (_Float16)h0[2]; a[3] = (_Float16)h0[3];
                a[4] = (_Float16)h1[0]; a[5] = (_Float16)h1[1]; a[6] = (_Float16)h1[2]; a[7] = (_Float16)h1[3];
                af[mt][kt] = a;
                const float p = (h0[0] + h0[1]) + (h0[2] + h0[3]) + (h1[0] + h1[1]) + (h1[2] + h1[3]);
                if (mt == 0) cs0 += p; else cs1 += p;
            }

        // ---- B fragments ----
        f16x8 bf[2][2];
#pragma unroll
        for (int nt = 0; nt < 2; ++nt)
#pragma unroll
            for (int kt = 0; kt < 2; ++kt) {
                const int row = w * 32 + nt * 16 + (lane & 15);
                const int g   = kt * 4 + (lane >> 4);
                bf[nt][kt] = *reinterpret_cast<const f16x8*>(&tile[row * 64 + ((g ^ (row & 7)) << 3)]);
            }

        // ---- 8 MFMAs ----
#pragma unroll
        for (int mt = 0; mt < 2; ++mt)
#pragma unroll
            for (int nt = 0; nt < 2; ++nt)
#pragma unroll
                for (int kt = 0; kt < 2; ++kt)
                    acc[mt][nt] = __builtin_amdgcn_mfma_f32_16x16x32_f16(
                        af[mt][kt], bf[nt][kt], acc[mt][nt], 0, 0, 0);

        if (s == 0) {
            // ---- transition to subtile 1: re-zero hist, atomics (lv1 in regs),
            //      then wait for prefetched data and stage ----
            barrier_nodrain();                // A/B-frag reads of s=0 retired
#pragma unroll
            for (int k = 0; k < 8; ++k) histf[tid + k * 256] = 0.f;
            barrier_nodrain();

            if ((unsigned)lv1[0] < 24u) atomicAdd(&histf[lv1[0] * 64 + HSWZ(lv1[0], cl)], 1.f);
            if ((unsigned)lv1[1] < 24u) atomicAdd(&histf[lv1[1] * 64 + HSWZ(lv1[1], cl)], 1.f);
            if ((unsigned)lv1[2] < 24u) atomicAdd(&histf[lv1[2] * 64 + HSWZ(lv1[2], cl)], 1.f);
            if ((unsigned)lv1[3] < 24u) atomicAdd(&histf[lv1[3] * 64 + HSWZ(lv1[3], cl)], 1.f);

            VMWAIT(0);                        // subtile-1 data landed
#pragma unroll
            for (int k = 0; k < 8; ++k) {
                const int ch = chb + k * 16;
                f16x4 hv;
                hv[0] = (_Float16)v[k][0]; hv[1] = (_Float16)v[k][1];
                hv[2] = (_Float16)v[k][2]; hv[3] = (_Float16)v[k][3];
                const int idx = ch * 64 + ((((q >> 1) ^ (ch & 7)) << 3) | ((q & 1) << 2));
                *reinterpret_cast<f16x4*>(&tile[idx]) = hv;
            }
            barrier_nodrain();
        }
    }

    // ---- counts: butterfly over 4 k-groups; wave 0 lanes write ----
    cs0 += __shfl_xor(cs0, 16, 64); cs0 += __shfl_xor(cs0, 32, 64);
    cs1 += __shfl_xor(cs1, 16, 64); cs1 += __shfl_xor(cs1, 32, 64);
    if (w == 0 && lane < 16) {
        cpart[(size_t)bid * NCLS + lane] = cs0;
        if (lane < 8) cpart[(size_t)bid * NCLS + 16 + lane] = cs1;
    }

    // ---- flush f16 per-block partials (non-atomic) ----
    _Float16* pblk = part + (size_t)bid * KCH;
#pragma unroll
    for (int mt = 0; mt < 2; ++mt)
#pragma unroll
        for (int nt = 0; nt < 2; ++nt)
#pragma unroll
            for (int rg = 0; rg < 4; ++rg) {
                const int cls = mt * 16 + (lane >> 4) * 4 + rg;   // C/D: row=(lane>>4)*4+reg
                const int ch  = w * 32 + nt * 16 + (lane & 15);   //      col=lane&15
                if (cls < NCLS) pblk[cls * NCH + ch] = (_Float16)acc[mt][nt][rg];
            }
}

// Grid 384 = (b, cls, ch-half). 4 waves reduce 32 g's each -> LDS -> wave-0 finish.
__global__ __launch_bounds__(256)
void fm_final(const _Float16* __restrict__ part, const float* __restrict__ cpart,
              float* __restrict__ out)
{
    __shared__ float red[256];
    __shared__ float credv[128];
    const int bid  = blockIdx.x;
    const int b    = bid / (NCLS * 2);
    const int rem  = bid % (NCLS * 2);
    const int cls  = rem >> 1;
    const int half = rem & 1;
    const int t    = threadIdx.x;
    const int c    = t & 63;
    const int gq   = t >> 6;

    if (t < 128) credv[t] = cpart[(size_t)(b * BPB + t) * NCLS + cls];

    const _Float16* pb = part + (size_t)(b * BPB + gq * 32) * KCH + cls * NCH + half * 64 + c;
    float s = 0.f;
#pragma unroll 8
    for (int g = 0; g < 32; ++g) s += (float)pb[(size_t)g * KCH];
    red[t] = s;
    __syncthreads();

    if (t < 64) {
        float cnt = credv[t] + credv[t + 64];
#pragma unroll
        for (int o = 32; o >= 1; o >>= 1) cnt += __shfl_xor(cnt, o, 64);
        const float sf = red[t] + red[t + 64] + red[t + 128] + red[t + 192];
        out[(size_t)b * KCH + (half * 64 + t) * NCLS + cls] = sf / (cnt + 1e-8f);  // (B,C,NCLS)
        if (t == 0 && half == 0) out[NF + b * NCLS + cls] = (cnt > 0.f) ? 1.f : 0.f;
    }
}

extern "C" void kernel_launch(void* const* d_in, const int* in_sizes, int n_in,
                              void* d_out, int out_size, void* d_ws, size_t ws_size,
                              hipStream_t stream) {
    const float* data  = (const float*)d_in[0];
    const int*   label = (const int*)d_in[1];
    float*     out   = (float*)d_out;
    _Float16*  part  = (_Float16*)d_ws;                          // NBLK*3072 f16 (6.3 MB)
    float*     cpart = (float*)(part + (size_t)NBLK * KCH);      // NBLK*24 f32

    fm_main<<<dim3(NBLK), dim3(256), 0, stream>>>(data, label, part, cpart);
    fm_final<<<dim3(NB * NCLS * 2), dim3(256), 0, stream>>>(part, cpart, out);
}